// Round 10
// baseline (1618.365 us; speedup 1.0000x reference)
//
#include <hip/hip_runtime.h>
#include <hip/hip_bf16.h>

// ---------------------------------------------------------------------------
// Model: self/ally tanh-Linear encoders -> segment mean -> cat MLP ->
//        8192-step LSTM (H=20) -> policy/value heads.
//   k_segmean : 1 wave/segment; fused bounds binary search; coalesced LDS tiles
//   k_feats   : 256-thr blocks; xg written PAIR-PACKED float2:
//               xgp2[t][j] = {row_j, row_j+40}, j in [0,40), pre-scaled by
//               log2e (i,f,o rows) / 2*log2e (g rows).
//   k_lstm    : single wave; lane k<20 -> (i_k,g_k), lane 32+k -> (f_k,o_k);
//               ONE float2 xg load/step; dots via v_pk_fma_f32 (h = SGPR
//               pairs); merged gate rcp R=rcp(d1*d2); o = d1*R (reuses d1);
//               hn = fma(2o, uc, -o) with free neg modifier; scaled cell
//               cs = 2*log2e*c; 8x unroll + 8-deep prefetch.
//   k_heads   : 256-thr blocks, float4 loads/stores
// ---------------------------------------------------------------------------

#define T_STEPS 8192
#define TOTAL_ROWS 1048576
#define DSELF 128
#define DALLY 64
#define HS 20
#define NOUT 16
#define L2E 1.44269504088896340736f

typedef float v2f __attribute__((ext_vector_type(2)));

__device__ __forceinline__ float rcp_f(float x) { return __builtin_amdgcn_rcpf(x); }
__device__ __forceinline__ float sigm_f(float x) { return rcp_f(1.0f + __expf(-x)); }
// tanh(x) = 2*sigmoid(2x) - 1 ; saturates correctly at +-inf
__device__ __forceinline__ float tanh_f(float x) { return fmaf(2.0f, sigm_f(2.0f * x), -1.0f); }

// packed fp32 FMA: acc.{lo,hi} += w.{lo,hi} * h.{lo,hi}; h is an SGPR pair.
__device__ __forceinline__ v2f pk_fma(v2f acc, v2f w, v2f h) {
  asm("v_pk_fma_f32 %0, %1, %2, %0" : "+v"(acc) : "v"(w), "s"(h));
  return acc;
}
__device__ __forceinline__ v2f pk_add(v2f a, v2f b) {
  v2f d;
  asm("v_pk_add_f32 %0, %1, %2" : "=v"(d) : "v"(a), "v"(b));
  return d;
}

// ------------------- K2: fused bounds + ally tanh-linear + segment mean -----
__global__ __launch_bounds__(64) void k_segmean(
    const float* __restrict__ ally, const int* __restrict__ seg,
    const float* __restrict__ W_ally, const float* __restrict__ b_ally,
    float* __restrict__ avg) {
  __shared__ float tile[64][DALLY + 2];
  __shared__ float red[64][HS + 1];
  const int lane = threadIdx.x;
  const int s = blockIdx.x;
  // wave-uniform binary searches (seg sorted, every segment nonempty)
  int r0;
  {
    int lo = 0, hi = TOTAL_ROWS;
    while (lo < hi) { int mid = (lo + hi) >> 1; if (seg[mid] < s) lo = mid + 1; else hi = mid; }
    r0 = lo;
  }
  int r1;
  if (s == T_STEPS - 1) {
    r1 = TOTAL_ROWS;
  } else {
    int lo = r0, hi = TOTAL_ROWS;
    const int sp = s + 1;
    while (lo < hi) { int mid = (lo + hi) >> 1; if (seg[mid] < sp) lo = mid + 1; else hi = mid; }
    r1 = lo;
  }
  float acc[HS];
#pragma unroll
  for (int h = 0; h < HS; ++h) acc[h] = 0.0f;
  for (int base = r0; base < r1; base += 64) {
    const int m = min(64, r1 - base);
    __syncthreads();  // protect tile from previous iteration's readers
    for (int idx = lane; idx < m * 16; idx += 64) {
      const int rr = idx >> 4, cc = (idx & 15) << 2;
      const float4 v = *reinterpret_cast<const float4*>(
          ally + (size_t)(base + rr) * DALLY + cc);
      *reinterpret_cast<float2*>(&tile[rr][cc])     = make_float2(v.x, v.y);
      *reinterpret_cast<float2*>(&tile[rr][cc + 2]) = make_float2(v.z, v.w);
    }
    __syncthreads();
    if (lane < m) {
      float dot[HS];
#pragma unroll
      for (int h = 0; h < HS; ++h) dot[h] = b_ally[h];  // uniform -> SGPR
#pragma unroll
      for (int j = 0; j < DALLY; j += 4) {
        const float2 xa = *reinterpret_cast<const float2*>(&tile[lane][j]);
        const float2 xb = *reinterpret_cast<const float2*>(&tile[lane][j + 2]);
#pragma unroll
        for (int h = 0; h < HS; ++h) {
          const float4 w = *reinterpret_cast<const float4*>(&W_ally[h * DALLY + j]);
          dot[h] = fmaf(xa.x, w.x, dot[h]);
          dot[h] = fmaf(xa.y, w.y, dot[h]);
          dot[h] = fmaf(xb.x, w.z, dot[h]);
          dot[h] = fmaf(xb.y, w.w, dot[h]);
        }
      }
#pragma unroll
      for (int h = 0; h < HS; ++h) acc[h] += tanh_f(dot[h]);
    }
  }
#pragma unroll
  for (int h = 0; h < HS; ++h) red[lane][h] = acc[h];
  __syncthreads();
  if (lane < HS) {
    float t = 0.0f;
    for (int l = 0; l < 64; ++l) t += red[l][lane];
    avg[(size_t)s * HS + lane] = t / (float)(r1 - r0);
  }
}

// ------------- K3: per-timestep features: s, cat, xg(packed), value ---------
__global__ __launch_bounds__(256) void k_feats(
    const float* __restrict__ self_in, const float* __restrict__ avg,
    const float* __restrict__ W_self, const float* __restrict__ b_self,
    const float* __restrict__ W_cat, const float* __restrict__ b_cat,
    const float* __restrict__ W_ih, const float* __restrict__ b_ih,
    const float* __restrict__ b_hh,
    const float* __restrict__ W_vfc, const float* __restrict__ b_vfc,
    const float* __restrict__ W_v, const float* __restrict__ b_v,
    float* __restrict__ xg, float* __restrict__ v_out) {
  __shared__ float s_ws[HS * DSELF];
  __shared__ float s_bs[HS];
  __shared__ float s_wc[HS * 2 * HS];
  __shared__ float s_bc[HS];
  __shared__ float s_wih[4 * HS * HS];
  __shared__ float s_bih[4 * HS];
  __shared__ float s_wv[HS * HS];
  __shared__ float s_bv[HS];
  __shared__ float s_wvv[HS];
  __shared__ float s_bvs;
  const int tid = threadIdx.x;
  for (int i = tid; i < HS * DSELF; i += 256) s_ws[i] = W_self[i];
  for (int i = tid; i < HS * 2 * HS; i += 256) s_wc[i] = W_cat[i];
  // exp2-folding: g rows ([800,1200)) scaled by 2*L2E, others by L2E.
  for (int i = tid; i < 4 * HS * HS; i += 256) {
    const float sc = (i >= 800 && i < 1200) ? (2.0f * L2E) : L2E;
    s_wih[i] = W_ih[i] * sc;
  }
  for (int i = tid; i < HS * HS; i += 256) s_wv[i] = W_vfc[i];
  if (tid < HS) {
    s_bs[tid] = b_self[tid]; s_bc[tid] = b_cat[tid];
    s_bv[tid] = b_vfc[tid];  s_wvv[tid] = W_v[tid];
  }
  if (tid < 4 * HS) {
    const float sc = (tid >= 40 && tid < 60) ? (2.0f * L2E) : L2E;
    s_bih[tid] = (b_ih[tid] + b_hh[tid]) * sc;
  }
  if (tid == 0) s_bvs = b_v[0];
  __syncthreads();

  const int t = blockIdx.x * 256 + tid;
  const float* srow = self_in + (size_t)t * DSELF;
  float acc[HS];
#pragma unroll
  for (int h = 0; h < HS; ++h) acc[h] = s_bs[h];
  for (int j = 0; j < DSELF / 4; ++j) {
    const float4 x = *reinterpret_cast<const float4*>(srow + j * 4);
#pragma unroll
    for (int h = 0; h < HS; ++h) {
      const float4 w = *reinterpret_cast<const float4*>(&s_ws[h * DSELF + j * 4]);
      acc[h] = fmaf(x.x, w.x, acc[h]);
      acc[h] = fmaf(x.y, w.y, acc[h]);
      acc[h] = fmaf(x.z, w.z, acc[h]);
      acc[h] = fmaf(x.w, w.w, acc[h]);
    }
  }
  float sv[HS], av[HS];
#pragma unroll
  for (int h = 0; h < HS; ++h) sv[h] = tanh_f(acc[h]);
  {
    const float4* ap = reinterpret_cast<const float4*>(avg + (size_t)t * HS);
#pragma unroll
    for (int q = 0; q < HS / 4; ++q) {
      const float4 a4 = ap[q];
      av[q * 4 + 0] = a4.x; av[q * 4 + 1] = a4.y;
      av[q * 4 + 2] = a4.z; av[q * 4 + 3] = a4.w;
    }
  }
  float cat[HS];
#pragma unroll
  for (int h = 0; h < HS; ++h) {
    float a = s_bc[h];
#pragma unroll
    for (int j = 0; j < HS; ++j) a = fmaf(sv[j], s_wc[h * 2 * HS + j], a);
#pragma unroll
    for (int j = 0; j < HS; ++j) a = fmaf(av[j], s_wc[h * 2 * HS + HS + j], a);
    cat[h] = tanh_f(a);
  }
  // PAIR-PACKED xg: float2[j] = {row_j, row_j+40}, j in [0,40).
  // Written as float4 covering float2-indices j, j+1.
#pragma unroll 2
  for (int j = 0; j < 40; j += 2) {
    float a0 = s_bih[j],      a1 = s_bih[j + 40];
    float a2 = s_bih[j + 1],  a3 = s_bih[j + 41];
#pragma unroll
    for (int k = 0; k < HS; ++k) {
      const float cv = cat[k];
      a0 = fmaf(cv, s_wih[(j + 0)  * HS + k], a0);
      a1 = fmaf(cv, s_wih[(j + 40) * HS + k], a1);
      a2 = fmaf(cv, s_wih[(j + 1)  * HS + k], a2);
      a3 = fmaf(cv, s_wih[(j + 41) * HS + k], a3);
    }
    float4 o4; o4.x = a0; o4.y = a1; o4.z = a2; o4.w = a3;
    *reinterpret_cast<float4*>(&xg[(size_t)t * 80 + 2 * j]) = o4;
  }
  float vacc = s_bvs;
#pragma unroll
  for (int h = 0; h < HS; ++h) {
    float a = s_bv[h];
#pragma unroll
    for (int k = 0; k < HS; ++k) a = fmaf(cat[k], s_wv[h * HS + k], a);
    vacc = fmaf(tanh_f(a), s_wvv[h], vacc);
  }
  v_out[t] = vacc;
}

// ----------------------------- K4: LSTM scan --------------------------------
// Single wave, exp2-folded, scaled cell, merged gate rcp, pair-packed xg:
//   X = {a1_pre, a2_pre} one float2 load/step.
//   e1=2^-a1, e2=2^-a2, d1=1+e1, d2=1+e2, R=rcp(d1*d2)
//   lanes 0-19:  P1 = [2L2E(1-e2)]*R = i * 2L2E*tanh(g)   (prod)
//   lanes 32-51: P1 = d2*R = f ;  P2 = d1*R = o
// f, o cross via permlane32_swap. cs' = f*cs + prod.
// hn = fma(2o, uc, -o) (neg modifier free). 8x unroll, 8-deep prefetch
// (tail reads spill <=2.6KB into hbuf region: valid, never consumed).
#define LSTM_STEP(X, K)                                                       \
  do {                                                                        \
    v2f pA = {(X).x, 0.0f}, pB = {0.0f, 0.0f};                                \
    v2f qA = {(X).y, 0.0f}, qB = {0.0f, 0.0f};                                \
    _Pragma("unroll") for (int j = 0; j < 10; j += 2) {                       \
      const v2f h2a = {hs[2 * j],     hs[2 * j + 1]};                         \
      const v2f h2b = {hs[2 * j + 2], hs[2 * j + 3]};                         \
      pA = pk_fma(pA, wa2[j],     h2a);                                       \
      qA = pk_fma(qA, wb2[j],     h2a);                                       \
      pB = pk_fma(pB, wa2[j + 1], h2b);                                       \
      qB = pk_fma(qB, wb2[j + 1], h2b);                                       \
    }                                                                         \
    pA = pk_add(pA, pB);                                                      \
    qA = pk_add(qA, qB);                                                      \
    const float a1 = pA.x + pA.y;                                             \
    const float a2 = qA.x + qA.y;                                             \
    (X) = pxp[(K + 8) * 40];                                                  \
    const float e1 = __builtin_amdgcn_exp2f(-a1);                             \
    const float e2 = __builtin_amdgcn_exp2f(-a2);                             \
    const float d1 = 1.0f + e1;                                               \
    const float d2 = 1.0f + e2;                                               \
    const float R  = rcp_f(d1 * d2);                                          \
    const float n  = fmaf(Bn, e2, An);   /* 2L2E(1-e2) | d2 */                \
    const float P1 = n * R;              /* prod | f */                       \
    const float P2 = d1 * R;             /* i(unused) | o */                  \
    auto rfp = __builtin_amdgcn_permlane32_swap(                              \
        __float_as_uint(P1), __float_as_uint(P1), false, false);              \
    auto rop = __builtin_amdgcn_permlane32_swap(                              \
        __float_as_uint(P2), __float_as_uint(P2), false, false);              \
    const float fp = __uint_as_float(rfp[1]);    /* lane k: f_k */            \
    const float op = __uint_as_float(rop[1]);    /* lane k: o_k */            \
    cs = fmaf(fp, cs, P1);                       /* scaled cell */            \
    const float op2 = op + op;                   /* off-path */               \
    const float ec = __builtin_amdgcn_exp2f(-cs);                             \
    const float uc = rcp_f(1.0f + ec);           /* sig(2c) */                \
    const float hn = fmaf(op2, uc, -op);         /* o * tanh(c) */            \
    if (lane < HS) hp[(K)*HS] = hn;                                           \
    const unsigned hu = __float_as_uint(hn);                                  \
    _Pragma("unroll") for (int j = 0; j < HS; ++j)                            \
        hs[j] = __uint_as_float(__builtin_amdgcn_readlane(hu, j));            \
  } while (0)

__global__ __launch_bounds__(64) void k_lstm(
    const float* __restrict__ xg, const float* __restrict__ Whh,
    const float* __restrict__ h0, const float* __restrict__ c0,
    float* __restrict__ hout) {
  const int lane = threadIdx.x;
  const int kk = lane & 31;
  const int kc = kk < HS ? kk : HS - 1;            // clamp dup lanes
  const int r1 = kc + ((lane >= 32) ? HS : 0);     // i rows | f rows
  const int r2 = r1 + 2 * HS;                      // g rows | o rows
  const int idx = ((lane >= 32) ? HS : 0) + kc;    // packed float2 index

  // merged-rcp lane constants: n = fma(Bn, e2, An)
  const float An = (lane < 32) ? 2.0f * L2E : 1.0f;
  const float Bn = (lane < 32) ? -2.0f * L2E : 1.0f;
  // W_hh row scales: pass1 (i,f) -> L2E; pass2 g -> 2L2E, o -> L2E
  const float s2v = (lane < 32) ? 2.0f * L2E : L2E;

  v2f wa2[10], wb2[10];
  {
    const v2f* ra = reinterpret_cast<const v2f*>(Whh + (size_t)r1 * HS);
    const v2f* rb = reinterpret_cast<const v2f*>(Whh + (size_t)r2 * HS);
#pragma unroll
    for (int j = 0; j < 10; ++j) {
      v2f a = ra[j], b = rb[j];
      a.x *= L2E; a.y *= L2E;
      b.x *= s2v; b.y *= s2v;
      wa2[j] = a; wb2[j] = b;
    }
  }

  float hs[HS];
#pragma unroll
  for (int j = 0; j < HS; ++j) hs[j] = h0[j];      // uniform -> s_load
  float cs = c0[kc] * (2.0f * L2E);                // scaled cell

  const v2f* pxp = reinterpret_cast<const v2f*>(xg) + idx;
  v2f X0 = pxp[0 * 40], X1 = pxp[1 * 40], X2 = pxp[2 * 40], X3 = pxp[3 * 40];
  v2f X4 = pxp[4 * 40], X5 = pxp[5 * 40], X6 = pxp[6 * 40], X7 = pxp[7 * 40];
  float* hp = hout + lane;

  for (int t = 0; t < T_STEPS; t += 8) {
    LSTM_STEP(X0, 0);
    LSTM_STEP(X1, 1);
    LSTM_STEP(X2, 2);
    LSTM_STEP(X3, 3);
    LSTM_STEP(X4, 4);
    LSTM_STEP(X5, 5);
    LSTM_STEP(X6, 6);
    LSTM_STEP(X7, 7);
    pxp += 8 * 40; hp += 8 * HS;
  }
}

// ----------------------------- K5: output heads ------------------------------
__global__ __launch_bounds__(256) void k_heads(
    const float* __restrict__ hbuf,
    const float* __restrict__ W_pfc, const float* __restrict__ b_pfc,
    const float* __restrict__ W_mu, const float* __restrict__ b_mu,
    const float* __restrict__ W_ls, const float* __restrict__ b_ls,
    float* __restrict__ mu_out, float* __restrict__ lso_out,
    float* __restrict__ ls_out) {
  __shared__ float wp[HS * HS], bp[HS], wm[NOUT * HS], bm[NOUT], wl[NOUT * HS], bl[NOUT];
  const int tid = threadIdx.x;
  for (int i = tid; i < HS * HS; i += 256) wp[i] = W_pfc[i];
  for (int i = tid; i < NOUT * HS; i += 256) { wm[i] = W_mu[i]; wl[i] = W_ls[i]; }
  if (tid < HS) bp[tid] = b_pfc[tid];
  if (tid < NOUT) { bm[tid] = b_mu[tid]; bl[tid] = b_ls[tid]; }
  __syncthreads();
  const int t = blockIdx.x * 256 + tid;
  float hr[HS];
  {
    const float4* hp4 = reinterpret_cast<const float4*>(hbuf + (size_t)t * HS);
#pragma unroll
    for (int q = 0; q < HS / 4; ++q) {
      const float4 h4 = hp4[q];
      hr[q * 4 + 0] = h4.x; hr[q * 4 + 1] = h4.y;
      hr[q * 4 + 2] = h4.z; hr[q * 4 + 3] = h4.w;
    }
  }
  float x[HS];
#pragma unroll
  for (int h = 0; h < HS; ++h) {
    float a = bp[h];
#pragma unroll
    for (int k = 0; k < HS; ++k) a = fmaf(hr[k], wp[h * HS + k], a);
    x[h] = tanh_f(a);
  }
  float4* mo4 = reinterpret_cast<float4*>(mu_out + (size_t)t * NOUT);
  float4* lo4 = reinterpret_cast<float4*>(lso_out + (size_t)t * NOUT);
  float4* lb4 = reinterpret_cast<float4*>(ls_out + (size_t)t * NOUT);
#pragma unroll
  for (int m = 0; m < NOUT; m += 4) {
    float4 mu4, lsb4, lso4;
    float am[4], bm_[4];
#pragma unroll
    for (int q = 0; q < 4; ++q) { am[q] = bm[m + q]; bm_[q] = bl[m + q]; }
#pragma unroll
    for (int k = 0; k < HS; ++k) {
      const float xv = x[k];
#pragma unroll
      for (int q = 0; q < 4; ++q) {
        am[q]  = fmaf(xv, wm[(m + q) * HS + k], am[q]);
        bm_[q] = fmaf(xv, wl[(m + q) * HS + k], bm_[q]);
      }
    }
    mu4.x = tanh_f(am[0]); mu4.y = tanh_f(am[1]);
    mu4.z = tanh_f(am[2]); mu4.w = tanh_f(am[3]);
    lsb4.x = bm_[0]; lsb4.y = bm_[1]; lsb4.z = bm_[2]; lsb4.w = bm_[3];
    lso4.x = __expf(fmaxf(bm_[0], 0.0f) - 2.0f);
    lso4.y = __expf(fmaxf(bm_[1], 0.0f) - 2.0f);
    lso4.z = __expf(fmaxf(bm_[2], 0.0f) - 2.0f);
    lso4.w = __expf(fmaxf(bm_[3], 0.0f) - 2.0f);
    mo4[m / 4] = mu4; lb4[m / 4] = lsb4; lo4[m / 4] = lso4;
  }
}

// ---------------------------------------------------------------------------
extern "C" void kernel_launch(void* const* d_in, const int* in_sizes, int n_in,
                              void* d_out, int out_size, void* d_ws, size_t ws_size,
                              hipStream_t stream) {
  const float* self_in = (const float*)d_in[0];
  const float* ally_in = (const float*)d_in[1];
  const int*   seg     = (const int*)d_in[2];
  const float* W_self  = (const float*)d_in[3];
  const float* b_self  = (const float*)d_in[4];
  const float* W_ally  = (const float*)d_in[5];
  const float* b_ally  = (const float*)d_in[6];
  const float* W_cat   = (const float*)d_in[7];
  const float* b_cat   = (const float*)d_in[8];
  const float* W_ih    = (const float*)d_in[9];
  const float* W_hh    = (const float*)d_in[10];
  const float* b_ih    = (const float*)d_in[11];
  const float* b_hh    = (const float*)d_in[12];
  const float* W_pfc   = (const float*)d_in[13];
  const float* b_pfc   = (const float*)d_in[14];
  const float* W_vfc   = (const float*)d_in[15];
  const float* b_vfc   = (const float*)d_in[16];
  const float* W_mu    = (const float*)d_in[17];
  const float* b_mu    = (const float*)d_in[18];
  const float* W_ls    = (const float*)d_in[19];
  const float* b_ls    = (const float*)d_in[20];
  const float* W_v     = (const float*)d_in[21];
  const float* b_v     = (const float*)d_in[22];
  const float* h0      = (const float*)d_in[23];
  const float* c0      = (const float*)d_in[24];
  float* out = (float*)d_out;

  // workspace layout (bytes): avg[T*20] @36864 | xg[T*80] | hbuf[T*20]
  char* ws = (char*)d_ws;
  float* avg   = (float*)(ws + 36864);
  float* xg    = (float*)(ws + 692224);
  float* hbuf  = (float*)(ws + 3313664);   // total ~3.97 MB

  // output layout: mu[T*16] | log_std_out[T*16] | v[T] | log_std[T*16]
  float* mu_out  = out;
  float* lso_out = out + 131072;
  float* v_out   = out + 262144;
  float* ls_out  = out + 270336;

  k_segmean<<<T_STEPS, 64, 0, stream>>>(ally_in, seg, W_ally, b_ally, avg);
  k_feats<<<T_STEPS / 256, 256, 0, stream>>>(self_in, avg, W_self, b_self,
                                             W_cat, b_cat, W_ih, b_ih, b_hh,
                                             W_vfc, b_vfc, W_v, b_v, xg, v_out);
  k_lstm<<<1, 64, 0, stream>>>(xg, W_hh, h0, c0, hbuf);
  k_heads<<<T_STEPS / 256, 256, 0, stream>>>(hbuf, W_pfc, b_pfc, W_mu, b_mu,
                                             W_ls, b_ls, mu_out, lso_out, ls_out);
}

// Round 11
// 1571.908 us; speedup vs baseline: 1.0296x; 1.0296x over previous
//
#include <hip/hip_runtime.h>
#include <hip/hip_bf16.h>

// ---------------------------------------------------------------------------
// Model: self/ally tanh-Linear encoders -> segment mean -> cat MLP ->
//        8192-step LSTM (H=20) -> policy/value heads.
//   k_bounds  : O(N) boundary scan (seg sorted, all segments nonempty ->
//               consecutive diffs <= 1): seg[i]!=seg[i-1] => start[seg[i]]=i
//   k_segmean : 1 wave/segment; start[] from k_bounds; coalesced LDS tiles
//   k_feats   : 256-thr blocks; xg row-major [t][80], pre-scaled by log2e
//               (i,f,o rows) / 2*log2e (g rows)
//   k_lstm    : single wave (R9 structure: two scalar xg loads -- packed
//               float2 load regressed in R10); merged gate rcp + d1-reuse:
//               R=rcp(d1*d2), f=d2*R, o=d1*R; hn=fma(2o,uc,-o) free neg;
//               scaled cell cs=2*log2e*c; 8x unroll + 8-deep prefetch
//   k_heads   : 256-thr blocks, float4 loads/stores
// ---------------------------------------------------------------------------

#define T_STEPS 8192
#define TOTAL_ROWS 1048576
#define DSELF 128
#define DALLY 64
#define HS 20
#define NOUT 16
#define L2E 1.44269504088896340736f

typedef float v2f __attribute__((ext_vector_type(2)));

__device__ __forceinline__ float rcp_f(float x) { return __builtin_amdgcn_rcpf(x); }
__device__ __forceinline__ float sigm_f(float x) { return rcp_f(1.0f + __expf(-x)); }
// tanh(x) = 2*sigmoid(2x) - 1 ; saturates correctly at +-inf
__device__ __forceinline__ float tanh_f(float x) { return fmaf(2.0f, sigm_f(2.0f * x), -1.0f); }

// packed fp32 FMA: acc.{lo,hi} += w.{lo,hi} * h.{lo,hi}; h is an SGPR pair.
__device__ __forceinline__ v2f pk_fma(v2f acc, v2f w, v2f h) {
  asm("v_pk_fma_f32 %0, %1, %2, %0" : "+v"(acc) : "v"(w), "s"(h));
  return acc;
}
__device__ __forceinline__ v2f pk_add(v2f a, v2f b) {
  v2f d;
  asm("v_pk_add_f32 %0, %1, %2" : "=v"(d) : "v"(a), "v"(b));
  return d;
}

// --------------------------- K1: segment boundaries (O(N) scan) -------------
__global__ __launch_bounds__(256) void k_bounds(const int* __restrict__ seg,
                                                int* __restrict__ start) {
  const int i = blockIdx.x * 256 + threadIdx.x;
  if (i >= TOTAL_ROWS) return;
  const int s = seg[i];
  if (i == 0) {
    start[0] = 0;
    start[T_STEPS] = TOTAL_ROWS;
  } else if (seg[i - 1] != s) {
    start[s] = i;   // all segments nonempty -> s == seg[i-1]+1
  }
}

// ------------------- K2: fused ally tanh-linear + segment mean --------------
__global__ __launch_bounds__(64) void k_segmean(
    const float* __restrict__ ally, const int* __restrict__ start,
    const float* __restrict__ W_ally, const float* __restrict__ b_ally,
    float* __restrict__ avg) {
  __shared__ float tile[64][DALLY + 2];
  __shared__ float red[64][HS + 1];
  const int lane = threadIdx.x;
  const int s = blockIdx.x;
  const int r0 = start[s], r1 = start[s + 1];   // uniform -> scalar loads
  float acc[HS];
#pragma unroll
  for (int h = 0; h < HS; ++h) acc[h] = 0.0f;
  for (int base = r0; base < r1; base += 64) {
    const int m = min(64, r1 - base);
    __syncthreads();  // protect tile from previous iteration's readers
    for (int idx = lane; idx < m * 16; idx += 64) {
      const int rr = idx >> 4, cc = (idx & 15) << 2;
      const float4 v = *reinterpret_cast<const float4*>(
          ally + (size_t)(base + rr) * DALLY + cc);
      *reinterpret_cast<float2*>(&tile[rr][cc])     = make_float2(v.x, v.y);
      *reinterpret_cast<float2*>(&tile[rr][cc + 2]) = make_float2(v.z, v.w);
    }
    __syncthreads();
    if (lane < m) {
      float dot[HS];
#pragma unroll
      for (int h = 0; h < HS; ++h) dot[h] = b_ally[h];  // uniform -> SGPR
#pragma unroll
      for (int j = 0; j < DALLY; j += 4) {
        const float2 xa = *reinterpret_cast<const float2*>(&tile[lane][j]);
        const float2 xb = *reinterpret_cast<const float2*>(&tile[lane][j + 2]);
#pragma unroll
        for (int h = 0; h < HS; ++h) {
          const float4 w = *reinterpret_cast<const float4*>(&W_ally[h * DALLY + j]);
          dot[h] = fmaf(xa.x, w.x, dot[h]);
          dot[h] = fmaf(xa.y, w.y, dot[h]);
          dot[h] = fmaf(xb.x, w.z, dot[h]);
          dot[h] = fmaf(xb.y, w.w, dot[h]);
        }
      }
#pragma unroll
      for (int h = 0; h < HS; ++h) acc[h] += tanh_f(dot[h]);
    }
  }
#pragma unroll
  for (int h = 0; h < HS; ++h) red[lane][h] = acc[h];
  __syncthreads();
  if (lane < HS) {
    float t = 0.0f;
    for (int l = 0; l < 64; ++l) t += red[l][lane];
    avg[(size_t)s * HS + lane] = t / (float)(r1 - r0);
  }
}

// ------------- K3: per-timestep features: s, cat, xg(scaled), value ---------
__global__ __launch_bounds__(256) void k_feats(
    const float* __restrict__ self_in, const float* __restrict__ avg,
    const float* __restrict__ W_self, const float* __restrict__ b_self,
    const float* __restrict__ W_cat, const float* __restrict__ b_cat,
    const float* __restrict__ W_ih, const float* __restrict__ b_ih,
    const float* __restrict__ b_hh,
    const float* __restrict__ W_vfc, const float* __restrict__ b_vfc,
    const float* __restrict__ W_v, const float* __restrict__ b_v,
    float* __restrict__ xg, float* __restrict__ v_out) {
  __shared__ float s_ws[HS * DSELF];
  __shared__ float s_bs[HS];
  __shared__ float s_wc[HS * 2 * HS];
  __shared__ float s_bc[HS];
  __shared__ float s_wih[4 * HS * HS];
  __shared__ float s_bih[4 * HS];
  __shared__ float s_wv[HS * HS];
  __shared__ float s_bv[HS];
  __shared__ float s_wvv[HS];
  __shared__ float s_bvs;
  const int tid = threadIdx.x;
  for (int i = tid; i < HS * DSELF; i += 256) s_ws[i] = W_self[i];
  for (int i = tid; i < HS * 2 * HS; i += 256) s_wc[i] = W_cat[i];
  // exp2-folding: g rows ([800,1200)) scaled by 2*L2E, others by L2E.
  for (int i = tid; i < 4 * HS * HS; i += 256) {
    const float sc = (i >= 800 && i < 1200) ? (2.0f * L2E) : L2E;
    s_wih[i] = W_ih[i] * sc;
  }
  for (int i = tid; i < HS * HS; i += 256) s_wv[i] = W_vfc[i];
  if (tid < HS) {
    s_bs[tid] = b_self[tid]; s_bc[tid] = b_cat[tid];
    s_bv[tid] = b_vfc[tid];  s_wvv[tid] = W_v[tid];
  }
  if (tid < 4 * HS) {
    const float sc = (tid >= 40 && tid < 60) ? (2.0f * L2E) : L2E;
    s_bih[tid] = (b_ih[tid] + b_hh[tid]) * sc;
  }
  if (tid == 0) s_bvs = b_v[0];
  __syncthreads();

  const int t = blockIdx.x * 256 + tid;
  const float* srow = self_in + (size_t)t * DSELF;
  float acc[HS];
#pragma unroll
  for (int h = 0; h < HS; ++h) acc[h] = s_bs[h];
  for (int j = 0; j < DSELF / 4; ++j) {
    const float4 x = *reinterpret_cast<const float4*>(srow + j * 4);
#pragma unroll
    for (int h = 0; h < HS; ++h) {
      const float4 w = *reinterpret_cast<const float4*>(&s_ws[h * DSELF + j * 4]);
      acc[h] = fmaf(x.x, w.x, acc[h]);
      acc[h] = fmaf(x.y, w.y, acc[h]);
      acc[h] = fmaf(x.z, w.z, acc[h]);
      acc[h] = fmaf(x.w, w.w, acc[h]);
    }
  }
  float sv[HS], av[HS];
#pragma unroll
  for (int h = 0; h < HS; ++h) sv[h] = tanh_f(acc[h]);
  {
    const float4* ap = reinterpret_cast<const float4*>(avg + (size_t)t * HS);
#pragma unroll
    for (int q = 0; q < HS / 4; ++q) {
      const float4 a4 = ap[q];
      av[q * 4 + 0] = a4.x; av[q * 4 + 1] = a4.y;
      av[q * 4 + 2] = a4.z; av[q * 4 + 3] = a4.w;
    }
  }
  float cat[HS];
#pragma unroll
  for (int h = 0; h < HS; ++h) {
    float a = s_bc[h];
#pragma unroll
    for (int j = 0; j < HS; ++j) a = fmaf(sv[j], s_wc[h * 2 * HS + j], a);
#pragma unroll
    for (int j = 0; j < HS; ++j) a = fmaf(av[j], s_wc[h * 2 * HS + HS + j], a);
    cat[h] = tanh_f(a);
  }
  // xg written as float4 groups of gate rows (scaled pre-activations),
  // row-major order i(0-19), f(20-39), g(40-59), o(60-79)
#pragma unroll 2
  for (int jj = 0; jj < 4 * HS; jj += 4) {
    float a0 = s_bih[jj], a1 = s_bih[jj + 1], a2 = s_bih[jj + 2], a3 = s_bih[jj + 3];
#pragma unroll
    for (int k = 0; k < HS; ++k) {
      const float cv = cat[k];
      a0 = fmaf(cv, s_wih[(jj + 0) * HS + k], a0);
      a1 = fmaf(cv, s_wih[(jj + 1) * HS + k], a1);
      a2 = fmaf(cv, s_wih[(jj + 2) * HS + k], a2);
      a3 = fmaf(cv, s_wih[(jj + 3) * HS + k], a3);
    }
    float4 o4; o4.x = a0; o4.y = a1; o4.z = a2; o4.w = a3;
    *reinterpret_cast<float4*>(&xg[(size_t)t * 80 + jj]) = o4;
  }
  float vacc = s_bvs;
#pragma unroll
  for (int h = 0; h < HS; ++h) {
    float a = s_bv[h];
#pragma unroll
    for (int k = 0; k < HS; ++k) a = fmaf(cat[k], s_wv[h * HS + k], a);
    vacc = fmaf(tanh_f(a), s_wvv[h], vacc);
  }
  v_out[t] = vacc;
}

// ----------------------------- K4: LSTM scan --------------------------------
// Single wave, exp2-folded, scaled cell, merged gate rcp with d1-reuse:
//   e1=2^-a1, e2=2^-a2, d1=1+e1, d2=1+e2, R=rcp(d1*d2)
//   lanes 0-19:  P1 = [2L2E(1-e2)]*R = i * 2L2E*tanh(g)   (prod)
//   lanes 32-51: P1 = d2*R = f ;  P2 = d1*R = o            (d1 reused)
// f, o cross via permlane32_swap. cs' = f*cs + prod.
// hn = fma(2o, uc, -o) (neg modifier free). Two independent scalar xg loads
// per step (packed float2 load regressed -- R10). 8x unroll, 8-deep prefetch
// (tail reads spill <=2.6KB into hbuf region: valid, never consumed).
#define LSTM_STEP(X1, X2, K)                                                  \
  do {                                                                        \
    v2f pA = {(X1), 0.0f}, pB = {0.0f, 0.0f};                                 \
    v2f qA = {(X2), 0.0f}, qB = {0.0f, 0.0f};                                 \
    _Pragma("unroll") for (int j = 0; j < 10; j += 2) {                       \
      const v2f h2a = {hs[2 * j],     hs[2 * j + 1]};                         \
      const v2f h2b = {hs[2 * j + 2], hs[2 * j + 3]};                         \
      pA = pk_fma(pA, wa2[j],     h2a);                                       \
      qA = pk_fma(qA, wb2[j],     h2a);                                       \
      pB = pk_fma(pB, wa2[j + 1], h2b);                                       \
      qB = pk_fma(qB, wb2[j + 1], h2b);                                       \
    }                                                                         \
    pA = pk_add(pA, pB);                                                      \
    qA = pk_add(qA, qB);                                                      \
    const float a1 = pA.x + pA.y;                                             \
    const float a2 = qA.x + qA.y;                                             \
    (X1) = px1[(K + 8) * 80];                                                 \
    (X2) = px2[(K + 8) * 80];                                                 \
    const float e1 = __builtin_amdgcn_exp2f(-a1);                             \
    const float e2 = __builtin_amdgcn_exp2f(-a2);                             \
    const float d1 = 1.0f + e1;                                               \
    const float d2 = 1.0f + e2;                                               \
    const float R  = rcp_f(d1 * d2);                                          \
    const float n  = fmaf(Bn, e2, An);   /* 2L2E(1-e2) | d2 */                \
    const float P1 = n * R;              /* prod | f */                       \
    const float P2 = d1 * R;             /* (unused) | o */                   \
    auto rfp = __builtin_amdgcn_permlane32_swap(                              \
        __float_as_uint(P1), __float_as_uint(P1), false, false);              \
    auto rop = __builtin_amdgcn_permlane32_swap(                              \
        __float_as_uint(P2), __float_as_uint(P2), false, false);              \
    const float fp = __uint_as_float(rfp[1]);    /* lane k: f_k */            \
    const float op = __uint_as_float(rop[1]);    /* lane k: o_k */            \
    cs = fmaf(fp, cs, P1);                       /* scaled cell */            \
    const float op2 = op + op;                   /* off-path */               \
    const float ec = __builtin_amdgcn_exp2f(-cs);                             \
    const float uc = rcp_f(1.0f + ec);           /* sig(2c) */                \
    const float hn = fmaf(op2, uc, -op);         /* o * tanh(c) */            \
    if (lane < HS) hp[(K)*HS] = hn;                                           \
    const unsigned hu = __float_as_uint(hn);                                  \
    _Pragma("unroll") for (int j = 0; j < HS; ++j)                            \
        hs[j] = __uint_as_float(__builtin_amdgcn_readlane(hu, j));            \
  } while (0)

__global__ __launch_bounds__(64) void k_lstm(
    const float* __restrict__ xg, const float* __restrict__ Whh,
    const float* __restrict__ h0, const float* __restrict__ c0,
    float* __restrict__ hout) {
  const int lane = threadIdx.x;
  const int kk = lane & 31;
  const int kc = kk < HS ? kk : HS - 1;            // clamp dup lanes
  const int r1 = kc + ((lane >= 32) ? HS : 0);     // i rows | f rows
  const int r2 = r1 + 2 * HS;                      // g rows | o rows

  // merged-rcp lane constants: n = fma(Bn, e2, An)
  const float An = (lane < 32) ? 2.0f * L2E : 1.0f;
  const float Bn = (lane < 32) ? -2.0f * L2E : 1.0f;
  // W_hh row scales: pass1 (i,f) -> L2E; pass2 g -> 2L2E, o -> L2E
  const float s2v = (lane < 32) ? 2.0f * L2E : L2E;

  v2f wa2[10], wb2[10];
  {
    const v2f* ra = reinterpret_cast<const v2f*>(Whh + (size_t)r1 * HS);
    const v2f* rb = reinterpret_cast<const v2f*>(Whh + (size_t)r2 * HS);
#pragma unroll
    for (int j = 0; j < 10; ++j) {
      v2f a = ra[j], b = rb[j];
      a.x *= L2E; a.y *= L2E;
      b.x *= s2v; b.y *= s2v;
      wa2[j] = a; wb2[j] = b;
    }
  }

  float hs[HS];
#pragma unroll
  for (int j = 0; j < HS; ++j) hs[j] = h0[j];      // uniform -> s_load
  float cs = c0[kc] * (2.0f * L2E);                // scaled cell

  const float* px1 = xg + r1;
  const float* px2 = xg + r2;
  float x10 = px1[0 * 80], x20 = px2[0 * 80];
  float x11 = px1[1 * 80], x21 = px2[1 * 80];
  float x12 = px1[2 * 80], x22 = px2[2 * 80];
  float x13 = px1[3 * 80], x23 = px2[3 * 80];
  float x14 = px1[4 * 80], x24 = px2[4 * 80];
  float x15 = px1[5 * 80], x25 = px2[5 * 80];
  float x16 = px1[6 * 80], x26 = px2[6 * 80];
  float x17 = px1[7 * 80], x27 = px2[7 * 80];
  float* hp = hout + lane;

  for (int t = 0; t < T_STEPS; t += 8) {
    LSTM_STEP(x10, x20, 0);
    LSTM_STEP(x11, x21, 1);
    LSTM_STEP(x12, x22, 2);
    LSTM_STEP(x13, x23, 3);
    LSTM_STEP(x14, x24, 4);
    LSTM_STEP(x15, x25, 5);
    LSTM_STEP(x16, x26, 6);
    LSTM_STEP(x17, x27, 7);
    px1 += 8 * 80; px2 += 8 * 80; hp += 8 * HS;
  }
}

// ----------------------------- K5: output heads ------------------------------
__global__ __launch_bounds__(256) void k_heads(
    const float* __restrict__ hbuf,
    const float* __restrict__ W_pfc, const float* __restrict__ b_pfc,
    const float* __restrict__ W_mu, const float* __restrict__ b_mu,
    const float* __restrict__ W_ls, const float* __restrict__ b_ls,
    float* __restrict__ mu_out, float* __restrict__ lso_out,
    float* __restrict__ ls_out) {
  __shared__ float wp[HS * HS], bp[HS], wm[NOUT * HS], bm[NOUT], wl[NOUT * HS], bl[NOUT];
  const int tid = threadIdx.x;
  for (int i = tid; i < HS * HS; i += 256) wp[i] = W_pfc[i];
  for (int i = tid; i < NOUT * HS; i += 256) { wm[i] = W_mu[i]; wl[i] = W_ls[i]; }
  if (tid < HS) bp[tid] = b_pfc[tid];
  if (tid < NOUT) { bm[tid] = b_mu[tid]; bl[tid] = b_ls[tid]; }
  __syncthreads();
  const int t = blockIdx.x * 256 + tid;
  float hr[HS];
  {
    const float4* hp4 = reinterpret_cast<const float4*>(hbuf + (size_t)t * HS);
#pragma unroll
    for (int q = 0; q < HS / 4; ++q) {
      const float4 h4 = hp4[q];
      hr[q * 4 + 0] = h4.x; hr[q * 4 + 1] = h4.y;
      hr[q * 4 + 2] = h4.z; hr[q * 4 + 3] = h4.w;
    }
  }
  float x[HS];
#pragma unroll
  for (int h = 0; h < HS; ++h) {
    float a = bp[h];
#pragma unroll
    for (int k = 0; k < HS; ++k) a = fmaf(hr[k], wp[h * HS + k], a);
    x[h] = tanh_f(a);
  }
  float4* mo4 = reinterpret_cast<float4*>(mu_out + (size_t)t * NOUT);
  float4* lo4 = reinterpret_cast<float4*>(lso_out + (size_t)t * NOUT);
  float4* lb4 = reinterpret_cast<float4*>(ls_out + (size_t)t * NOUT);
#pragma unroll
  for (int m = 0; m < NOUT; m += 4) {
    float4 mu4, lsb4, lso4;
    float am[4], bm_[4];
#pragma unroll
    for (int q = 0; q < 4; ++q) { am[q] = bm[m + q]; bm_[q] = bl[m + q]; }
#pragma unroll
    for (int k = 0; k < HS; ++k) {
      const float xv = x[k];
#pragma unroll
      for (int q = 0; q < 4; ++q) {
        am[q]  = fmaf(xv, wm[(m + q) * HS + k], am[q]);
        bm_[q] = fmaf(xv, wl[(m + q) * HS + k], bm_[q]);
      }
    }
    mu4.x = tanh_f(am[0]); mu4.y = tanh_f(am[1]);
    mu4.z = tanh_f(am[2]); mu4.w = tanh_f(am[3]);
    lsb4.x = bm_[0]; lsb4.y = bm_[1]; lsb4.z = bm_[2]; lsb4.w = bm_[3];
    lso4.x = __expf(fmaxf(bm_[0], 0.0f) - 2.0f);
    lso4.y = __expf(fmaxf(bm_[1], 0.0f) - 2.0f);
    lso4.z = __expf(fmaxf(bm_[2], 0.0f) - 2.0f);
    lso4.w = __expf(fmaxf(bm_[3], 0.0f) - 2.0f);
    mo4[m / 4] = mu4; lb4[m / 4] = lsb4; lo4[m / 4] = lso4;
  }
}

// ---------------------------------------------------------------------------
extern "C" void kernel_launch(void* const* d_in, const int* in_sizes, int n_in,
                              void* d_out, int out_size, void* d_ws, size_t ws_size,
                              hipStream_t stream) {
  const float* self_in = (const float*)d_in[0];
  const float* ally_in = (const float*)d_in[1];
  const int*   seg     = (const int*)d_in[2];
  const float* W_self  = (const float*)d_in[3];
  const float* b_self  = (const float*)d_in[4];
  const float* W_ally  = (const float*)d_in[5];
  const float* b_ally  = (const float*)d_in[6];
  const float* W_cat   = (const float*)d_in[7];
  const float* b_cat   = (const float*)d_in[8];
  const float* W_ih    = (const float*)d_in[9];
  const float* W_hh    = (const float*)d_in[10];
  const float* b_ih    = (const float*)d_in[11];
  const float* b_hh    = (const float*)d_in[12];
  const float* W_pfc   = (const float*)d_in[13];
  const float* b_pfc   = (const float*)d_in[14];
  const float* W_vfc   = (const float*)d_in[15];
  const float* b_vfc   = (const float*)d_in[16];
  const float* W_mu    = (const float*)d_in[17];
  const float* b_mu    = (const float*)d_in[18];
  const float* W_ls    = (const float*)d_in[19];
  const float* b_ls    = (const float*)d_in[20];
  const float* W_v     = (const float*)d_in[21];
  const float* b_v     = (const float*)d_in[22];
  const float* h0      = (const float*)d_in[23];
  const float* c0      = (const float*)d_in[24];
  float* out = (float*)d_out;

  // workspace layout (bytes): start[8193] @0 | avg[T*20] @36864 | xg[T*80] |
  // hbuf[T*20]; total ~3.97 MB
  char* ws = (char*)d_ws;
  int*   start = (int*)(ws);
  float* avg   = (float*)(ws + 36864);
  float* xg    = (float*)(ws + 692224);
  float* hbuf  = (float*)(ws + 3313664);

  // output layout: mu[T*16] | log_std_out[T*16] | v[T] | log_std[T*16]
  float* mu_out  = out;
  float* lso_out = out + 131072;
  float* v_out   = out + 262144;
  float* ls_out  = out + 270336;

  k_bounds<<<TOTAL_ROWS / 256, 256, 0, stream>>>(seg, start);
  k_segmean<<<T_STEPS, 64, 0, stream>>>(ally_in, start, W_ally, b_ally, avg);
  k_feats<<<T_STEPS / 256, 256, 0, stream>>>(self_in, avg, W_self, b_self,
                                             W_cat, b_cat, W_ih, b_ih, b_hh,
                                             W_vfc, b_vfc, W_v, b_v, xg, v_out);
  k_lstm<<<1, 64, 0, stream>>>(xg, W_hh, h0, c0, hbuf);
  k_heads<<<T_STEPS / 256, 256, 0, stream>>>(hbuf, W_pfc, b_pfc, W_mu, b_mu,
                                             W_ls, b_ls, mu_out, lso_out, ls_out);
}

// Round 12
// 1542.895 us; speedup vs baseline: 1.0489x; 1.0188x over previous
//
#include <hip/hip_runtime.h>
#include <hip/hip_bf16.h>

// ---------------------------------------------------------------------------
// Model: self/ally tanh-Linear encoders -> segment mean -> cat MLP ->
//        8192-step LSTM (H=20) -> policy/value heads.
// LOCK-IN build: best measured variant of each kernel.
//   k_bounds  : O(N) boundary scan (R11, -26us residue)
//   k_segmean : 1 wave/segment; coalesced LDS tiles (R4)
//   k_feats   : 256-thr blocks; xg row-major, exp2-pre-scaled (R8)
//   k_lstm    : EXACT R9 body (1337us best measured). Single wave; merged
//               gate rcp (one rcp per 2 sigmoids); v_pk_fma_f32 dots with
//               h as SGPR pairs; scaled cell cs=2*log2e*c; permlane32_swap
//               for f,o; 8x unroll + 8-deep scalar xg prefetch.
//               Rejected (measured worse): wave-ring handoff (+300us),
//               packed float2 xg load (+46us), d1-reuse o-gate (+28us).
//   k_heads   : 256-thr blocks, float4 loads/stores
// ---------------------------------------------------------------------------

#define T_STEPS 8192
#define TOTAL_ROWS 1048576
#define DSELF 128
#define DALLY 64
#define HS 20
#define NOUT 16
#define L2E 1.44269504088896340736f

typedef float v2f __attribute__((ext_vector_type(2)));

__device__ __forceinline__ float rcp_f(float x) { return __builtin_amdgcn_rcpf(x); }
__device__ __forceinline__ float sigm_f(float x) { return rcp_f(1.0f + __expf(-x)); }
// tanh(x) = 2*sigmoid(2x) - 1 ; saturates correctly at +-inf
__device__ __forceinline__ float tanh_f(float x) { return fmaf(2.0f, sigm_f(2.0f * x), -1.0f); }

// packed fp32 FMA: acc.{lo,hi} += w.{lo,hi} * h.{lo,hi}; h is an SGPR pair.
__device__ __forceinline__ v2f pk_fma(v2f acc, v2f w, v2f h) {
  asm("v_pk_fma_f32 %0, %1, %2, %0" : "+v"(acc) : "v"(w), "s"(h));
  return acc;
}
__device__ __forceinline__ v2f pk_add(v2f a, v2f b) {
  v2f d;
  asm("v_pk_add_f32 %0, %1, %2" : "=v"(d) : "v"(a), "v"(b));
  return d;
}

// --------------------------- K1: segment boundaries (O(N) scan) -------------
__global__ __launch_bounds__(256) void k_bounds(const int* __restrict__ seg,
                                                int* __restrict__ start) {
  const int i = blockIdx.x * 256 + threadIdx.x;
  if (i >= TOTAL_ROWS) return;
  const int s = seg[i];
  if (i == 0) {
    start[0] = 0;
    start[T_STEPS] = TOTAL_ROWS;
  } else if (seg[i - 1] != s) {
    start[s] = i;   // all segments nonempty -> s == seg[i-1]+1
  }
}

// ------------------- K2: fused ally tanh-linear + segment mean --------------
__global__ __launch_bounds__(64) void k_segmean(
    const float* __restrict__ ally, const int* __restrict__ start,
    const float* __restrict__ W_ally, const float* __restrict__ b_ally,
    float* __restrict__ avg) {
  __shared__ float tile[64][DALLY + 2];
  __shared__ float red[64][HS + 1];
  const int lane = threadIdx.x;
  const int s = blockIdx.x;
  const int r0 = start[s], r1 = start[s + 1];   // uniform -> scalar loads
  float acc[HS];
#pragma unroll
  for (int h = 0; h < HS; ++h) acc[h] = 0.0f;
  for (int base = r0; base < r1; base += 64) {
    const int m = min(64, r1 - base);
    __syncthreads();  // protect tile from previous iteration's readers
    for (int idx = lane; idx < m * 16; idx += 64) {
      const int rr = idx >> 4, cc = (idx & 15) << 2;
      const float4 v = *reinterpret_cast<const float4*>(
          ally + (size_t)(base + rr) * DALLY + cc);
      *reinterpret_cast<float2*>(&tile[rr][cc])     = make_float2(v.x, v.y);
      *reinterpret_cast<float2*>(&tile[rr][cc + 2]) = make_float2(v.z, v.w);
    }
    __syncthreads();
    if (lane < m) {
      float dot[HS];
#pragma unroll
      for (int h = 0; h < HS; ++h) dot[h] = b_ally[h];  // uniform -> SGPR
#pragma unroll
      for (int j = 0; j < DALLY; j += 4) {
        const float2 xa = *reinterpret_cast<const float2*>(&tile[lane][j]);
        const float2 xb = *reinterpret_cast<const float2*>(&tile[lane][j + 2]);
#pragma unroll
        for (int h = 0; h < HS; ++h) {
          const float4 w = *reinterpret_cast<const float4*>(&W_ally[h * DALLY + j]);
          dot[h] = fmaf(xa.x, w.x, dot[h]);
          dot[h] = fmaf(xa.y, w.y, dot[h]);
          dot[h] = fmaf(xb.x, w.z, dot[h]);
          dot[h] = fmaf(xb.y, w.w, dot[h]);
        }
      }
#pragma unroll
      for (int h = 0; h < HS; ++h) acc[h] += tanh_f(dot[h]);
    }
  }
#pragma unroll
  for (int h = 0; h < HS; ++h) red[lane][h] = acc[h];
  __syncthreads();
  if (lane < HS) {
    float t = 0.0f;
    for (int l = 0; l < 64; ++l) t += red[l][lane];
    avg[(size_t)s * HS + lane] = t / (float)(r1 - r0);
  }
}

// ------------- K3: per-timestep features: s, cat, xg(scaled), value ---------
__global__ __launch_bounds__(256) void k_feats(
    const float* __restrict__ self_in, const float* __restrict__ avg,
    const float* __restrict__ W_self, const float* __restrict__ b_self,
    const float* __restrict__ W_cat, const float* __restrict__ b_cat,
    const float* __restrict__ W_ih, const float* __restrict__ b_ih,
    const float* __restrict__ b_hh,
    const float* __restrict__ W_vfc, const float* __restrict__ b_vfc,
    const float* __restrict__ W_v, const float* __restrict__ b_v,
    float* __restrict__ xg, float* __restrict__ v_out) {
  __shared__ float s_ws[HS * DSELF];
  __shared__ float s_bs[HS];
  __shared__ float s_wc[HS * 2 * HS];
  __shared__ float s_bc[HS];
  __shared__ float s_wih[4 * HS * HS];
  __shared__ float s_bih[4 * HS];
  __shared__ float s_wv[HS * HS];
  __shared__ float s_bv[HS];
  __shared__ float s_wvv[HS];
  __shared__ float s_bvs;
  const int tid = threadIdx.x;
  for (int i = tid; i < HS * DSELF; i += 256) s_ws[i] = W_self[i];
  for (int i = tid; i < HS * 2 * HS; i += 256) s_wc[i] = W_cat[i];
  // exp2-folding: g rows ([800,1200)) scaled by 2*L2E, others by L2E.
  for (int i = tid; i < 4 * HS * HS; i += 256) {
    const float sc = (i >= 800 && i < 1200) ? (2.0f * L2E) : L2E;
    s_wih[i] = W_ih[i] * sc;
  }
  for (int i = tid; i < HS * HS; i += 256) s_wv[i] = W_vfc[i];
  if (tid < HS) {
    s_bs[tid] = b_self[tid]; s_bc[tid] = b_cat[tid];
    s_bv[tid] = b_vfc[tid];  s_wvv[tid] = W_v[tid];
  }
  if (tid < 4 * HS) {
    const float sc = (tid >= 40 && tid < 60) ? (2.0f * L2E) : L2E;
    s_bih[tid] = (b_ih[tid] + b_hh[tid]) * sc;
  }
  if (tid == 0) s_bvs = b_v[0];
  __syncthreads();

  const int t = blockIdx.x * 256 + tid;
  const float* srow = self_in + (size_t)t * DSELF;
  float acc[HS];
#pragma unroll
  for (int h = 0; h < HS; ++h) acc[h] = s_bs[h];
  for (int j = 0; j < DSELF / 4; ++j) {
    const float4 x = *reinterpret_cast<const float4*>(srow + j * 4);
#pragma unroll
    for (int h = 0; h < HS; ++h) {
      const float4 w = *reinterpret_cast<const float4*>(&s_ws[h * DSELF + j * 4]);
      acc[h] = fmaf(x.x, w.x, acc[h]);
      acc[h] = fmaf(x.y, w.y, acc[h]);
      acc[h] = fmaf(x.z, w.z, acc[h]);
      acc[h] = fmaf(x.w, w.w, acc[h]);
    }
  }
  float sv[HS], av[HS];
#pragma unroll
  for (int h = 0; h < HS; ++h) sv[h] = tanh_f(acc[h]);
  {
    const float4* ap = reinterpret_cast<const float4*>(avg + (size_t)t * HS);
#pragma unroll
    for (int q = 0; q < HS / 4; ++q) {
      const float4 a4 = ap[q];
      av[q * 4 + 0] = a4.x; av[q * 4 + 1] = a4.y;
      av[q * 4 + 2] = a4.z; av[q * 4 + 3] = a4.w;
    }
  }
  float cat[HS];
#pragma unroll
  for (int h = 0; h < HS; ++h) {
    float a = s_bc[h];
#pragma unroll
    for (int j = 0; j < HS; ++j) a = fmaf(sv[j], s_wc[h * 2 * HS + j], a);
#pragma unroll
    for (int j = 0; j < HS; ++j) a = fmaf(av[j], s_wc[h * 2 * HS + HS + j], a);
    cat[h] = tanh_f(a);
  }
  // xg written as float4 groups of gate rows (scaled pre-activations),
  // row-major order i(0-19), f(20-39), g(40-59), o(60-79)
#pragma unroll 2
  for (int jj = 0; jj < 4 * HS; jj += 4) {
    float a0 = s_bih[jj], a1 = s_bih[jj + 1], a2 = s_bih[jj + 2], a3 = s_bih[jj + 3];
#pragma unroll
    for (int k = 0; k < HS; ++k) {
      const float cv = cat[k];
      a0 = fmaf(cv, s_wih[(jj + 0) * HS + k], a0);
      a1 = fmaf(cv, s_wih[(jj + 1) * HS + k], a1);
      a2 = fmaf(cv, s_wih[(jj + 2) * HS + k], a2);
      a3 = fmaf(cv, s_wih[(jj + 3) * HS + k], a3);
    }
    float4 o4; o4.x = a0; o4.y = a1; o4.z = a2; o4.w = a3;
    *reinterpret_cast<float4*>(&xg[(size_t)t * 80 + jj]) = o4;
  }
  float vacc = s_bvs;
#pragma unroll
  for (int h = 0; h < HS; ++h) {
    float a = s_bv[h];
#pragma unroll
    for (int k = 0; k < HS; ++k) a = fmaf(cat[k], s_wv[h * HS + k], a);
    vacc = fmaf(tanh_f(a), s_wvv[h], vacc);
  }
  v_out[t] = vacc;
}

// ----------------------------- K4: LSTM scan (exact R9 body) ----------------
// Single wave, exp2-folded, scaled cell, merged gate rcp:
//   e1=2^-a1, e2=2^-a2, D=(1+e1)(1+e2), R=rcp(D)
//   lanes 0-19:  P1 = n*R = [2L2E(1-e2)]*R = i * 2L2E*tanh(g)   (prod)
//   lanes 32-51: P1 = n*R = (1+e2)*R = f ;  P2 = m*R = 2(1+e1)*R = 2o
//   (n via lane-const fma; m = fma(2,e1,2) uniform)
// f, 2o cross to lanes 0-19 via permlane32_swap. cs' = f*cs + prod.
// hn = fma(op2, uc, ho), ho = -0.5*op2 under the cell-exp shadow.
// 8x unroll, 8-deep prefetch (tail reads spill <=2.6KB into hbuf region:
// valid memory, values never consumed).
#define LSTM_STEP(X1, X2, K)                                                  \
  do {                                                                        \
    v2f pA = {(X1), 0.0f}, pB = {0.0f, 0.0f};                                 \
    v2f qA = {(X2), 0.0f}, qB = {0.0f, 0.0f};                                 \
    _Pragma("unroll") for (int j = 0; j < 10; j += 2) {                       \
      const v2f h2a = {hs[2 * j],     hs[2 * j + 1]};                         \
      const v2f h2b = {hs[2 * j + 2], hs[2 * j + 3]};                         \
      pA = pk_fma(pA, wa2[j],     h2a);                                       \
      qA = pk_fma(qA, wb2[j],     h2a);                                       \
      pB = pk_fma(pB, wa2[j + 1], h2b);                                       \
      qB = pk_fma(qB, wb2[j + 1], h2b);                                       \
    }                                                                         \
    pA = pk_add(pA, pB);                                                      \
    qA = pk_add(qA, qB);                                                      \
    const float a1 = pA.x + pA.y;                                             \
    const float a2 = qA.x + qA.y;                                             \
    (X1) = px1[(K + 8) * 80];                                                 \
    (X2) = px2[(K + 8) * 80];                                                 \
    const float e1 = __builtin_amdgcn_exp2f(-a1);                             \
    const float e2 = __builtin_amdgcn_exp2f(-a2);                             \
    const float d1 = 1.0f + e1;                                               \
    const float d2 = 1.0f + e2;                                               \
    const float R  = rcp_f(d1 * d2);                                          \
    const float n  = fmaf(Bn, e2, An);   /* 2L2E(1-e2) | (1+e2) */            \
    const float m  = fmaf(2.0f, e1, 2.0f); /* - | 2(1+e1) */                  \
    const float P1 = n * R;              /* prod | f */                       \
    const float P2 = m * R;              /* -    | 2o */                      \
    auto rfp = __builtin_amdgcn_permlane32_swap(                              \
        __float_as_uint(P1), __float_as_uint(P1), false, false);              \
    auto rop = __builtin_amdgcn_permlane32_swap(                              \
        __float_as_uint(P2), __float_as_uint(P2), false, false);              \
    const float fp  = __uint_as_float(rfp[1]);   /* lane k: f_k */            \
    const float op2 = __uint_as_float(rop[1]);   /* lane k: 2*o_k */          \
    cs = fmaf(fp, cs, P1);                       /* scaled cell */            \
    const float ho = -0.5f * op2;                /* off-path */               \
    const float ec = __builtin_amdgcn_exp2f(-cs);                             \
    const float uc = rcp_f(1.0f + ec);           /* sig(2c) */                \
    const float hn = fmaf(op2, uc, ho);          /* o * tanh(c) */            \
    if (lane < HS) hp[(K)*HS] = hn;                                           \
    const unsigned hu = __float_as_uint(hn);                                  \
    _Pragma("unroll") for (int j = 0; j < HS; ++j)                            \
        hs[j] = __uint_as_float(__builtin_amdgcn_readlane(hu, j));            \
  } while (0)

__global__ __launch_bounds__(64) void k_lstm(
    const float* __restrict__ xg, const float* __restrict__ Whh,
    const float* __restrict__ h0, const float* __restrict__ c0,
    float* __restrict__ hout) {
  const int lane = threadIdx.x;
  const int kk = lane & 31;
  const int kc = kk < HS ? kk : HS - 1;            // clamp dup lanes
  const int r1 = kc + ((lane >= 32) ? HS : 0);     // i rows | f rows
  const int r2 = r1 + 2 * HS;                      // g rows | o rows

  // merged-rcp lane constants: n = fma(Bn, e2, An)
  const float An = (lane < 32) ? 2.0f * L2E : 1.0f;
  const float Bn = (lane < 32) ? -2.0f * L2E : 1.0f;
  // W_hh row scales: pass1 (i,f) -> L2E; pass2 g -> 2L2E, o -> L2E
  const float s2v = (lane < 32) ? 2.0f * L2E : L2E;

  v2f wa2[10], wb2[10];
  {
    const v2f* ra = reinterpret_cast<const v2f*>(Whh + (size_t)r1 * HS);
    const v2f* rb = reinterpret_cast<const v2f*>(Whh + (size_t)r2 * HS);
#pragma unroll
    for (int j = 0; j < 10; ++j) {
      v2f a = ra[j], b = rb[j];
      a.x *= L2E; a.y *= L2E;
      b.x *= s2v; b.y *= s2v;
      wa2[j] = a; wb2[j] = b;
    }
  }

  float hs[HS];
#pragma unroll
  for (int j = 0; j < HS; ++j) hs[j] = h0[j];      // uniform -> s_load
  float cs = c0[kc] * (2.0f * L2E);                // scaled cell

  const float* px1 = xg + r1;
  const float* px2 = xg + r2;
  float x10 = px1[0 * 80], x20 = px2[0 * 80];
  float x11 = px1[1 * 80], x21 = px2[1 * 80];
  float x12 = px1[2 * 80], x22 = px2[2 * 80];
  float x13 = px1[3 * 80], x23 = px2[3 * 80];
  float x14 = px1[4 * 80], x24 = px2[4 * 80];
  float x15 = px1[5 * 80], x25 = px2[5 * 80];
  float x16 = px1[6 * 80], x26 = px2[6 * 80];
  float x17 = px1[7 * 80], x27 = px2[7 * 80];
  float* hp = hout + lane;

  for (int t = 0; t < T_STEPS; t += 8) {
    LSTM_STEP(x10, x20, 0);
    LSTM_STEP(x11, x21, 1);
    LSTM_STEP(x12, x22, 2);
    LSTM_STEP(x13, x23, 3);
    LSTM_STEP(x14, x24, 4);
    LSTM_STEP(x15, x25, 5);
    LSTM_STEP(x16, x26, 6);
    LSTM_STEP(x17, x27, 7);
    px1 += 8 * 80; px2 += 8 * 80; hp += 8 * HS;
  }
}

// ----------------------------- K5: output heads ------------------------------
__global__ __launch_bounds__(256) void k_heads(
    const float* __restrict__ hbuf,
    const float* __restrict__ W_pfc, const float* __restrict__ b_pfc,
    const float* __restrict__ W_mu, const float* __restrict__ b_mu,
    const float* __restrict__ W_ls, const float* __restrict__ b_ls,
    float* __restrict__ mu_out, float* __restrict__ lso_out,
    float* __restrict__ ls_out) {
  __shared__ float wp[HS * HS], bp[HS], wm[NOUT * HS], bm[NOUT], wl[NOUT * HS], bl[NOUT];
  const int tid = threadIdx.x;
  for (int i = tid; i < HS * HS; i += 256) wp[i] = W_pfc[i];
  for (int i = tid; i < NOUT * HS; i += 256) { wm[i] = W_mu[i]; wl[i] = W_ls[i]; }
  if (tid < HS) bp[tid] = b_pfc[tid];
  if (tid < NOUT) { bm[tid] = b_mu[tid]; bl[tid] = b_ls[tid]; }
  __syncthreads();
  const int t = blockIdx.x * 256 + tid;
  float hr[HS];
  {
    const float4* hp4 = reinterpret_cast<const float4*>(hbuf + (size_t)t * HS);
#pragma unroll
    for (int q = 0; q < HS / 4; ++q) {
      const float4 h4 = hp4[q];
      hr[q * 4 + 0] = h4.x; hr[q * 4 + 1] = h4.y;
      hr[q * 4 + 2] = h4.z; hr[q * 4 + 3] = h4.w;
    }
  }
  float x[HS];
#pragma unroll
  for (int h = 0; h < HS; ++h) {
    float a = bp[h];
#pragma unroll
    for (int k = 0; k < HS; ++k) a = fmaf(hr[k], wp[h * HS + k], a);
    x[h] = tanh_f(a);
  }
  float4* mo4 = reinterpret_cast<float4*>(mu_out + (size_t)t * NOUT);
  float4* lo4 = reinterpret_cast<float4*>(lso_out + (size_t)t * NOUT);
  float4* lb4 = reinterpret_cast<float4*>(ls_out + (size_t)t * NOUT);
#pragma unroll
  for (int m = 0; m < NOUT; m += 4) {
    float4 mu4, lsb4, lso4;
    float am[4], bm_[4];
#pragma unroll
    for (int q = 0; q < 4; ++q) { am[q] = bm[m + q]; bm_[q] = bl[m + q]; }
#pragma unroll
    for (int k = 0; k < HS; ++k) {
      const float xv = x[k];
#pragma unroll
      for (int q = 0; q < 4; ++q) {
        am[q]  = fmaf(xv, wm[(m + q) * HS + k], am[q]);
        bm_[q] = fmaf(xv, wl[(m + q) * HS + k], bm_[q]);
      }
    }
    mu4.x = tanh_f(am[0]); mu4.y = tanh_f(am[1]);
    mu4.z = tanh_f(am[2]); mu4.w = tanh_f(am[3]);
    lsb4.x = bm_[0]; lsb4.y = bm_[1]; lsb4.z = bm_[2]; lsb4.w = bm_[3];
    lso4.x = __expf(fmaxf(bm_[0], 0.0f) - 2.0f);
    lso4.y = __expf(fmaxf(bm_[1], 0.0f) - 2.0f);
    lso4.z = __expf(fmaxf(bm_[2], 0.0f) - 2.0f);
    lso4.w = __expf(fmaxf(bm_[3], 0.0f) - 2.0f);
    mo4[m / 4] = mu4; lb4[m / 4] = lsb4; lo4[m / 4] = lso4;
  }
}

// ---------------------------------------------------------------------------
extern "C" void kernel_launch(void* const* d_in, const int* in_sizes, int n_in,
                              void* d_out, int out_size, void* d_ws, size_t ws_size,
                              hipStream_t stream) {
  const float* self_in = (const float*)d_in[0];
  const float* ally_in = (const float*)d_in[1];
  const int*   seg     = (const int*)d_in[2];
  const float* W_self  = (const float*)d_in[3];
  const float* b_self  = (const float*)d_in[4];
  const float* W_ally  = (const float*)d_in[5];
  const float* b_ally  = (const float*)d_in[6];
  const float* W_cat   = (const float*)d_in[7];
  const float* b_cat   = (const float*)d_in[8];
  const float* W_ih    = (const float*)d_in[9];
  const float* W_hh    = (const float*)d_in[10];
  const float* b_ih    = (const float*)d_in[11];
  const float* b_hh    = (const float*)d_in[12];
  const float* W_pfc   = (const float*)d_in[13];
  const float* b_pfc   = (const float*)d_in[14];
  const float* W_vfc   = (const float*)d_in[15];
  const float* b_vfc   = (const float*)d_in[16];
  const float* W_mu    = (const float*)d_in[17];
  const float* b_mu    = (const float*)d_in[18];
  const float* W_ls    = (const float*)d_in[19];
  const float* b_ls    = (const float*)d_in[20];
  const float* W_v     = (const float*)d_in[21];
  const float* b_v     = (const float*)d_in[22];
  const float* h0      = (const float*)d_in[23];
  const float* c0      = (const float*)d_in[24];
  float* out = (float*)d_out;

  // workspace layout (bytes): start[8193] @0 | avg[T*20] @36864 | xg[T*80] |
  // hbuf[T*20]; total ~3.97 MB
  char* ws = (char*)d_ws;
  int*   start = (int*)(ws);
  float* avg   = (float*)(ws + 36864);
  float* xg    = (float*)(ws + 692224);
  float* hbuf  = (float*)(ws + 3313664);

  // output layout: mu[T*16] | log_std_out[T*16] | v[T] | log_std[T*16]
  float* mu_out  = out;
  float* lso_out = out + 131072;
  float* v_out   = out + 262144;
  float* ls_out  = out + 270336;

  k_bounds<<<TOTAL_ROWS / 256, 256, 0, stream>>>(seg, start);
  k_segmean<<<T_STEPS, 64, 0, stream>>>(ally_in, start, W_ally, b_ally, avg);
  k_feats<<<T_STEPS / 256, 256, 0, stream>>>(self_in, avg, W_self, b_self,
                                             W_cat, b_cat, W_ih, b_ih, b_hh,
                                             W_vfc, b_vfc, W_v, b_v, xg, v_out);
  k_lstm<<<1, 64, 0, stream>>>(xg, W_hh, h0, c0, hbuf);
  k_heads<<<T_STEPS / 256, 256, 0, stream>>>(hbuf, W_pfc, b_pfc, W_mu, b_mu,
                                             W_ls, b_ls, mu_out, lso_out, ls_out);
}